// Round 6
// baseline (5290.255 us; speedup 1.0000x reference)
//
#include <hip/hip_runtime.h>
#include <math.h>

#define B_     128
#define L_     100
#define HID_   256
#define IND_   160
#define NCLASS 19
#define CAPD   16
#define NI     1600      // L_ * NUM_CAPS
#define OD     304       // NCLASS * CAPD
#define ENTITY 68

// ---------------------------------------------------------------------------
// Phase 0: embedding gather -> emb [b*L_+t][160]
// ---------------------------------------------------------------------------
__global__ void emb_gather(const int* __restrict__ word, const int* __restrict__ tag,
                           const int* __restrict__ pos1, const int* __restrict__ pos2,
                           const float* __restrict__ we, const float* __restrict__ te,
                           const float* __restrict__ p1e, const float* __restrict__ p2e,
                           float* __restrict__ emb)
{
    int idx = blockIdx.x * 256 + threadIdx.x;          // exactly B_*L_*IND_ threads
    int bt = idx / IND_;
    int k  = idx - bt * IND_;
    float v;
    if (k < 100)      v = we[word[bt] * 100 + k];
    else if (k < 120) v = te[tag[bt] * 20 + (k - 100)];
    else if (k < 140) v = p1e[pos1[bt] * 20 + (k - 120)];
    else              v = p2e[pos2[bt] * 20 + (k - 140)];
    emb[idx] = v;
}

// ---------------------------------------------------------------------------
// Phase 1: input-gate GEMM.  NEW xg layout: [dir][t][b(128)][gj(1024)]
// ---------------------------------------------------------------------------
__global__ void __launch_bounds__(256) gemm_xg(
    const float* __restrict__ emb,
    const float* __restrict__ wihf, const float* __restrict__ bihf, const float* __restrict__ bhhf,
    const float* __restrict__ wihb, const float* __restrict__ bihb, const float* __restrict__ bhhb,
    float* __restrict__ xg)
{
    int gt  = blockIdx.x;
    int t   = blockIdx.y;
    int dir = blockIdx.z;
    const float* w  = dir ? wihb : wihf;
    const float* bi = dir ? bihb : bihf;
    const float* bh = dir ? bhhb : bhhf;
    int gj0 = gt * 128;

    __shared__ float wsh[32][132];   // [k][gj], padded
    __shared__ float esh[32][132];   // [k][b],  padded

    int tid = threadIdx.x;
    int tx = tid & 15, ty = tid >> 4;

    float acc[8][8];
    #pragma unroll
    for (int i = 0; i < 8; ++i)
        #pragma unroll
        for (int j = 0; j < 8; ++j) acc[i][j] = 0.f;

    for (int k0 = 0; k0 < IND_; k0 += 32) {
        __syncthreads();
        #pragma unroll
        for (int m = 0; m < 16; ++m) {
            int e = m * 256 + tid;        // 0..4095
            int k = e & 31, g = e >> 5;   // g: row (gj or b)
            wsh[k][g] = w[(gj0 + g) * IND_ + k0 + k];
            esh[k][g] = emb[(g * L_ + t) * IND_ + k0 + k];
        }
        __syncthreads();
        #pragma unroll
        for (int k = 0; k < 32; ++k) {
            float wv[8], ev[8];
            #pragma unroll
            for (int q = 0; q < 8; ++q) wv[q] = wsh[k][ty * 8 + q];
            #pragma unroll
            for (int q = 0; q < 8; ++q) ev[q] = esh[k][tx * 8 + q];
            #pragma unroll
            for (int i = 0; i < 8; ++i)
                #pragma unroll
                for (int j = 0; j < 8; ++j) acc[i][j] = fmaf(wv[i], ev[j], acc[i][j]);
        }
    }
    #pragma unroll
    for (int i = 0; i < 8; ++i) {
        int gj = gj0 + ty * 8 + i;
        float bias = bi[gj] + bh[gj];
        #pragma unroll
        for (int j = 0; j < 8; ++j) {
            int b = tx * 8 + j;
            xg[(((size_t)dir * L_ + t) * 128 + b) * 1024 + gj] = acc[i][j] + bias;
        }
    }
}

// ---------------------------------------------------------------------------
// Phase 2: BiLSTM scan v6 — WEIGHT-RESIDENT. Block = (dir, b): 256 blocks x
// 512 threads, 1 block/CU. thread (j = tid>>1, kc = tid&1) owns 4 gates x
// 128 k. Weights bf16-packed, loaded ONCE: 96 k in 192 VGPRs + 32 k in LDS
// (128 KB). Zero global weight traffic in the scan loop (kills the 30us/step
// per-CU weight-stream bound of R2-R5). h fp32 in LDS (2 KB, broadcast reads,
// double-buffered, 1 barrier/step). Model: ~1100 VALU inst/thread/step x
// 2 waves/SIMD -> ~1.8 us/step -> ~250 us scan.
// ---------------------------------------------------------------------------
__device__ __forceinline__ float sigm_f(float x) { return 1.f / (1.f + __expf(-x)); }
__device__ __forceinline__ float tanh_f(float x) {
    float e = __expf(-2.f * fabsf(x));        // in (0,1], never overflows
    float r = (1.f - e) / (1.f + e);
    return copysignf(r, x);
}
__device__ __forceinline__ unsigned short f2bf(float f) {
    unsigned u = __float_as_uint(f);
    return (unsigned short)((u + 0x7fffu + ((u >> 16) & 1u)) >> 16);   // RNE
}
__device__ __forceinline__ unsigned packbf2(float lo, float hi) {
    return (unsigned)f2bf(lo) | ((unsigned)f2bf(hi) << 16);
}
#define BFLO(w) __uint_as_float((w) << 16)
#define BFHI(w) __uint_as_float((w) & 0xffff0000u)

__global__ void __launch_bounds__(512, 2) lstm_scan_f(
    const float* __restrict__ xg,
    const float* __restrict__ whhf, const float* __restrict__ whhb,
    float* __restrict__ xf, float* __restrict__ xb)
{
    int blk = blockIdx.x;          // 256 blocks
    int dir = blk >> 7;            // 0..1
    int b   = blk & 127;           // batch
    int tid = threadIdx.x;         // 0..511
    int kc  = tid & 1;
    int j   = tid >> 1;            // 0..255

    const float* whh = dir ? whhb : whhf;
    float* xo = dir ? xb : xf;

    __shared__ float hs[2][HID_];        //  2 KB: [buf][k]
    __shared__ uint4 wlds[16 * 512];     // 128 KB: [chunk(g*4+q)][tid]

    // ---- one-time weight preload: fp32 d_in -> bf16 packed regs + LDS ----
    const float* wrow0 = whh + ((size_t)(0 * HID_ + j)) * HID_ + kc * 128;
    const float* wrow1 = whh + ((size_t)(1 * HID_ + j)) * HID_ + kc * 128;
    const float* wrow2 = whh + ((size_t)(2 * HID_ + j)) * HID_ + kc * 128;
    const float* wrow3 = whh + ((size_t)(3 * HID_ + j)) * HID_ + kc * 128;
    const float* wrows[4] = { wrow0, wrow1, wrow2, wrow3 };

    unsigned wreg[192];            // 4 gates x 48 pairs (k 0..95 of this kc-half)
    #pragma unroll
    for (int g = 0; g < 4; ++g) {
        #pragma unroll
        for (int p = 0; p < 48; ++p) {
            float2 f2 = *(const float2*)(wrows[g] + 2 * p);
            wreg[g * 48 + p] = packbf2(f2.x, f2.y);
        }
    }
    #pragma unroll
    for (int g = 0; g < 4; ++g) {
        #pragma unroll
        for (int q = 0; q < 4; ++q) {
            int k0 = 96 + q * 8;
            float2 p0 = *(const float2*)(wrows[g] + k0 + 0);
            float2 p1 = *(const float2*)(wrows[g] + k0 + 2);
            float2 p2 = *(const float2*)(wrows[g] + k0 + 4);
            float2 p3 = *(const float2*)(wrows[g] + k0 + 6);
            uint4 v;
            v.x = packbf2(p0.x, p0.y); v.y = packbf2(p1.x, p1.y);
            v.z = packbf2(p2.x, p2.y); v.w = packbf2(p3.x, p3.y);
            wlds[(g * 4 + q) * 512 + tid] = v;
        }
    }
    if (kc == 0) hs[0][j] = 0.f;
    float c = 0.f;
    __syncthreads();

    for (int t = 0; t < L_; ++t) {
        int slot = dir ? (L_ - 1 - t) : t;
        int buf = t & 1;
        // gate precomputes (independent of h -> issue first)
        const float* xgb = xg + (((size_t)dir * L_ + slot) * 128 + b) * 1024 + j;
        float gp0 = xgb[0], gp1 = xgb[256], gp2 = xgb[512], gp3 = xgb[768];

        const float4* hp = (const float4*)&hs[buf][kc * 128];
        float a[4] = { 0.f, 0.f, 0.f, 0.f };

        // register-resident part: k 0..95 of this kc-half
        #pragma unroll
        for (int j4 = 0; j4 < 24; ++j4) {
            float4 hv = hp[j4];
            #pragma unroll
            for (int g = 0; g < 4; ++g) {
                unsigned w0 = wreg[g * 48 + 2 * j4];
                unsigned w1 = wreg[g * 48 + 2 * j4 + 1];
                a[g] = fmaf(BFLO(w0), hv.x, a[g]);
                a[g] = fmaf(BFHI(w0), hv.y, a[g]);
                a[g] = fmaf(BFLO(w1), hv.z, a[g]);
                a[g] = fmaf(BFHI(w1), hv.w, a[g]);
            }
        }
        // LDS-resident tail: k 96..127 of this kc-half
        #pragma unroll
        for (int g = 0; g < 4; ++g) {
            #pragma unroll
            for (int q = 0; q < 4; ++q) {
                uint4 wv = wlds[(g * 4 + q) * 512 + tid];
                float4 h0 = hp[24 + 2 * q];
                float4 h1 = hp[24 + 2 * q + 1];
                a[g] = fmaf(BFLO(wv.x), h0.x, a[g]);
                a[g] = fmaf(BFHI(wv.x), h0.y, a[g]);
                a[g] = fmaf(BFLO(wv.y), h0.z, a[g]);
                a[g] = fmaf(BFHI(wv.y), h0.w, a[g]);
                a[g] = fmaf(BFLO(wv.z), h1.x, a[g]);
                a[g] = fmaf(BFHI(wv.z), h1.y, a[g]);
                a[g] = fmaf(BFLO(wv.w), h1.z, a[g]);
                a[g] = fmaf(BFHI(wv.w), h1.w, a[g]);
            }
        }
        // reduce across the 2 kc lanes (lane xor 1, in-wave)
        #pragma unroll
        for (int g = 0; g < 4; ++g) a[g] += __shfl_xor(a[g], 1);

        float ai = a[0] + gp0, af = a[1] + gp1, ag = a[2] + gp2, ao = a[3] + gp3;
        float ig = sigm_f(ai), fg = sigm_f(af), gg = tanh_f(ag), og = sigm_f(ao);
        c = fg * c + ig * gg;
        float h = og * tanh_f(c);

        if (kc == 0) {
            hs[buf ^ 1][j] = h;
            xo[((size_t)slot * 128 + b) * 256 + j] = h;   // [l][b][j] block-contiguous
        }
        __syncthreads();
    }
}

// ---------------------------------------------------------------------------
// transpose-add: x[l][j][b] = xf[l][b][j] + xb[l][b][j]   (32x32 LDS tiles)
// grid (8, 4, 100), block 256 (= 32 x 8, 4 rows/thread)
// ---------------------------------------------------------------------------
__global__ void __launch_bounds__(256) xpose_add(
    const float* __restrict__ xf, const float* __restrict__ xb, float* __restrict__ x)
{
    int jt = blockIdx.x * 32, bt = blockIdx.y * 32, l = blockIdx.z;
    __shared__ float tsh[32][33];
    int tx = threadIdx.x & 31, ty = threadIdx.x >> 5;   // tx 0..31, ty 0..7
    #pragma unroll
    for (int r = 0; r < 4; ++r) {
        int bb = bt + ty * 4 + r;
        size_t src = ((size_t)l * 128 + bb) * 256 + jt + tx;
        tsh[ty * 4 + r][tx] = xf[src] + xb[src];
    }
    __syncthreads();
    #pragma unroll
    for (int r = 0; r < 4; ++r) {
        int jj = jt + ty * 4 + r;
        x[((size_t)l * 256 + jj) * 128 + bt + tx] = tsh[tx][ty * 4 + r];
    }
}

// ---------------------------------------------------------------------------
// Phase 3: entity features, attention, primary capsules (x is [l][j][b])
// ---------------------------------------------------------------------------
__global__ void find_entity(const int* __restrict__ pos1, const int* __restrict__ pos2,
                            int* __restrict__ e)
{
    int b = threadIdx.x;
    int e1 = 0, e2 = 0;
    for (int l = L_ - 1; l >= 0; --l) if (pos1[b * L_ + l] == ENTITY) e1 = l;
    for (int l = L_ - 1; l >= 0; --l) if (pos2[b * L_ + l] == ENTITY) e2 = l;
    e[b] = e1; e[B_ + b] = e2;
}

__global__ void compute_he(const float* __restrict__ x, const int* __restrict__ e,
                           float* __restrict__ he)
{
    int j = blockIdx.x, b = threadIdx.x;
    int e1 = e[b], e2 = e[B_ + b];
    he[j * B_ + b] = x[((size_t)e1 * HID_ + j) * B_ + b] + x[((size_t)e2 * HID_ + j) * B_ + b];
}

__global__ void att_logits(const float* __restrict__ x, const float* __restrict__ he,
                           float* __restrict__ logits)
{
    int l = blockIdx.x, b = threadIdx.x;
    float acc = 0.f;
    for (int j = 0; j < HID_; ++j)
        acc = fmaf(x[((size_t)l * HID_ + j) * B_ + b], he[j * B_ + b], acc);
    logits[l * B_ + b] = acc;
}

__global__ void att_softmax(const float* __restrict__ logits, float* __restrict__ att)
{
    int b = threadIdx.x;
    float m = -1e30f;
    for (int l = 0; l < L_; ++l) m = fmaxf(m, logits[l * B_ + b]);
    float s = 0.f;
    for (int l = 0; l < L_; ++l) s += expf(logits[l * B_ + b] - m);
    float inv = 1.f / s;
    for (int l = 0; l < L_; ++l) att[l * B_ + b] = expf(logits[l * B_ + b] - m) * inv;
}

// primary capsules: u[i][b][c], squashed
__global__ void u_squash(const float* __restrict__ x, float* __restrict__ u)
{
    int i = blockIdx.x, b = threadIdx.x;
    int l = i >> 4, cap = i & 15;
    float vals[16]; float n2 = 0.f;
    #pragma unroll
    for (int c2 = 0; c2 < 16; ++c2) {
        float v = x[((size_t)l * HID_ + cap * 16 + c2) * B_ + b];
        vals[c2] = v; n2 = fmaf(v, v, n2);
    }
    float f = (n2 / (1.f + n2)) / sqrtf(n2 + 1e-9f);
    #pragma unroll
    for (int c2 = 0; c2 < 16; ++c2)
        u[((size_t)i * B_ + b) * 16 + c2] = vals[c2] * f;
}

// ---------------------------------------------------------------------------
// Phase 4: routing
// ---------------------------------------------------------------------------
__global__ void bb_init(const float* __restrict__ br, float* __restrict__ bb)
{
    int idx = blockIdx.x * 256 + threadIdx.x;   // exactly B_*NI*NCLASS threads
    bb[idx] = br[idx % (NI * NCLASS)];
}

__global__ void __launch_bounds__(320) s_pass(
    const float* __restrict__ u, const float* __restrict__ W,
    const float* __restrict__ bb, const float* __restrict__ att,
    float* __restrict__ partial)
{
    int ic = blockIdx.x, bt = blockIdx.y;
    int i0 = ic * 16, b0 = bt * 16;
    __shared__ float C[16][16][20];   // [bl][il][o], padded
    int tid = threadIdx.x;
    if (tid < 256) {
        int bl = tid >> 4, il = tid & 15;
        int b = b0 + bl, i = i0 + il;
        const float* bbp = bb + ((size_t)b * NI + i) * NCLASS;
        float m = bbp[0];
        #pragma unroll
        for (int o = 1; o < NCLASS; ++o) m = fmaxf(m, bbp[o]);
        float s = 0.f; float e[NCLASS];
        #pragma unroll
        for (int o = 0; o < NCLASS; ++o) { e[o] = expf(bbp[o] - m); s += e[o]; }
        float al = att[(i >> 4) * B_ + b] / s;
        #pragma unroll
        for (int o = 0; o < NCLASS; ++o) C[bl][il][o] = e[o] * al;
    }
    __syncthreads();
    if (tid >= OD) return;
    int od = tid, o = od >> 4;
    float acc[16];
    #pragma unroll
    for (int bl = 0; bl < 16; ++bl) acc[bl] = 0.f;
    for (int il = 0; il < 16; ++il) {
        int i = i0 + il;
        const float* wp = W + (size_t)i * 16 * OD + od;
        float w[16];
        #pragma unroll
        for (int c2 = 0; c2 < 16; ++c2) w[c2] = wp[c2 * OD];     // coalesced over od
        const float* up = u + ((size_t)i * B_ + b0) * 16;        // uniform -> s_load
        #pragma unroll
        for (int bl = 0; bl < 16; ++bl) {
            float uh = 0.f;
            #pragma unroll
            for (int c2 = 0; c2 < 16; ++c2) uh = fmaf(up[bl * 16 + c2], w[c2], uh);
            acc[bl] = fmaf(C[bl][il][o], uh, acc[bl]);
        }
    }
    #pragma unroll
    for (int bl = 0; bl < 16; ++bl)
        partial[((size_t)ic * B_ + b0 + bl) * OD + od] = acc[bl];
}

__global__ void s_reduce(const float* __restrict__ partial, float* __restrict__ s)
{
    int idx = blockIdx.x * 256 + threadIdx.x;   // exactly B_*OD threads
    int b = idx / OD, od = idx - b * OD;
    float acc = 0.f;
    for (int ic = 0; ic < 100; ++ic) acc += partial[((size_t)ic * B_ + b) * OD + od];
    s[idx] = acc;
}

__global__ void squash_v(const float* __restrict__ s, float* __restrict__ v,
                         float* __restrict__ out, int write_out)
{
    int idx = blockIdx.x * 256 + threadIdx.x;
    if (idx >= B_ * NCLASS) return;
    const float* sp = s + (size_t)idx * 16;     // b*304 + o*16 == idx*16
    float vals[16]; float n2 = 0.f;
    #pragma unroll
    for (int d = 0; d < 16; ++d) { vals[d] = sp[d]; n2 = fmaf(vals[d], vals[d], n2); }
    float f = (n2 / (1.f + n2)) / sqrtf(n2 + 1e-9f);
    float n2v = 0.f;
    #pragma unroll
    for (int d = 0; d < 16; ++d) {
        float vv = vals[d] * f;
        v[(size_t)idx * 16 + d] = vv;
        n2v = fmaf(vv, vv, n2v);
    }
    if (write_out) out[idx] = sqrtf(n2v + 1e-9f);
}

__global__ void __launch_bounds__(320) bb_pass(
    const float* __restrict__ u, const float* __restrict__ W,
    const float* __restrict__ v, float* __restrict__ bb)
{
    int ic = blockIdx.x, bt = blockIdx.y;
    int i0 = ic * 16, b0 = bt * 16;
    int tid = threadIdx.x;
    if (tid >= OD) return;
    int od = tid, o = od >> 4, d = od & 15;
    float vv[16];
    #pragma unroll
    for (int bl = 0; bl < 16; ++bl) vv[bl] = v[(size_t)(b0 + bl) * OD + od];
    for (int il = 0; il < 16; ++il) {
        int i = i0 + il;
        const float* wp = W + (size_t)i * 16 * OD + od;
        float w[16];
        #pragma unroll
        for (int c2 = 0; c2 < 16; ++c2) w[c2] = wp[c2 * OD];
        const float* up = u + ((size_t)i * B_ + b0) * 16;
        #pragma unroll
        for (int bl = 0; bl < 16; ++bl) {
            float uh = 0.f;
            #pragma unroll
            for (int c2 = 0; c2 < 16; ++c2) uh = fmaf(up[bl * 16 + c2], w[c2], uh);
            float p = uh * vv[bl];
            p += __shfl_xor(p, 1);
            p += __shfl_xor(p, 2);
            p += __shfl_xor(p, 4);
            p += __shfl_xor(p, 8);
            if (d == 0) bb[((size_t)(b0 + bl) * NI + i) * NCLASS + o] += p;
        }
    }
}

// ---------------------------------------------------------------------------
extern "C" void kernel_launch(void* const* d_in, const int* in_sizes, int n_in,
                              void* d_out, int out_size, void* d_ws, size_t ws_size,
                              hipStream_t stream)
{
    (void)in_sizes; (void)n_in; (void)out_size; (void)ws_size;
    const int*   word = (const int*)d_in[0];
    const int*   tag  = (const int*)d_in[1];
    const int*   pos1 = (const int*)d_in[2];
    const int*   pos2 = (const int*)d_in[3];
    const float* we   = (const float*)d_in[4];
    const float* te   = (const float*)d_in[5];
    const float* p1e  = (const float*)d_in[6];
    const float* p2e  = (const float*)d_in[7];
    const float* wihf = (const float*)d_in[8];
    const float* whhf = (const float*)d_in[9];
    const float* bihf = (const float*)d_in[10];
    const float* bhhf = (const float*)d_in[11];
    const float* wihb = (const float*)d_in[12];
    const float* whhb = (const float*)d_in[13];
    const float* bihb = (const float*)d_in[14];
    const float* bhhb = (const float*)d_in[15];
    const float* Wc   = (const float*)d_in[16];
    const float* br   = (const float*)d_in[17];

    float* wsp    = (float*)d_ws;
    float* emb    = wsp;                       //  2,048,000
    float* xg     = wsp + 2048000;             // 26,214,400
    float* xf     = xg + 26214400;             //  3,276,800  [l][b][j]
    float* xb     = xf + 3276800;              //  3,276,800  [l][b][j]
    float* he     = xb + 3276800;              //     32,768
    float* logits = he + 32768;                //     12,800
    float* att    = logits + 12800;            //     12,800
    int*   e      = (int*)(att + 12800);       //        256 ints
    // post-scan buffers alias the (dead-after-scan) xg region
    float* x    = xg;                          //  3,276,800  [l][j][b]
    float* u    = xg + 3276800;                //  3,276,800
    float* bb   = xg + 6553600;                //  3,891,200
    float* part = xg + 10444800;               //  3,891,200
    float* s    = xg + 14336000;               //     38,912
    float* v    = s + 38912;                   //     38,912
    float* out  = (float*)d_out;

    emb_gather<<<8000, 256, 0, stream>>>(word, tag, pos1, pos2, we, te, p1e, p2e, emb);
    gemm_xg<<<dim3(8, 100, 2), 256, 0, stream>>>(emb, wihf, bihf, bhhf, wihb, bihb, bhhb, xg);
    lstm_scan_f<<<256, 512, 0, stream>>>(xg, whhf, whhb, xf, xb);
    xpose_add<<<dim3(8, 4, 100), 256, 0, stream>>>(xf, xb, x);
    find_entity<<<1, 128, 0, stream>>>(pos1, pos2, e);
    compute_he<<<256, 128, 0, stream>>>(x, e, he);
    att_logits<<<100, 128, 0, stream>>>(x, he, logits);
    att_softmax<<<1, 128, 0, stream>>>(logits, att);
    u_squash<<<1600, 128, 0, stream>>>(x, u);
    bb_init<<<15200, 256, 0, stream>>>(br, bb);
    for (int it = 0; it < 3; ++it) {
        s_pass<<<dim3(100, 8), 320, 0, stream>>>(u, Wc, bb, att, part);
        s_reduce<<<152, 256, 0, stream>>>(part, s);
        squash_v<<<10, 256, 0, stream>>>(s, v, out, (it == 2) ? 1 : 0);
        if (it < 2) bb_pass<<<dim3(100, 8), 320, 0, stream>>>(u, Wc, v, bb);
    }
}